// Round 10
// baseline (5559.286 us; speedup 1.0000x reference)
//
#include <hip/hip_runtime.h>

#define N_USERC 50000
#define N_ITEMC 100000
#define NN      150000      // total nodes
#define DD      64
#define NLAYER  3
#define NNZC    2400000
#define BB      4096
#define NRID    (3*BB)      // 12288 gathered output rows
#define NBKT    147         // ceil(NN/1024) row buckets (row>>10)
#define NABLK   586         // ceil(NNZC/4096) partition blocks
#define NDTILE  2344        // ceil(NN/64) dense tiles

typedef unsigned short ushort_t;
typedef __attribute__((ext_vector_type(4))) float float4v;

static __device__ __forceinline__ float bf2f(ushort_t b) {
    unsigned int u = ((unsigned int)b) << 16;
    return __uint_as_float(u);
}
static __device__ __forceinline__ ushort_t f2bf(float f) {
    unsigned int u = __float_as_uint(f);
    u = u + 0x7FFFu + ((u >> 16) & 1u);   // round-to-nearest-even
    return (ushort_t)(u >> 16);
}

// ---- dtype sniff: flag=1 if float inputs are packed bf16, 0 if fp32 ----
__global__ __launch_bounds__(64) void k_sniff(const unsigned int* __restrict__ ue_words,
                                              int* __restrict__ flag) {
    int lane = threadIdx.x;
    int cnt = 0;
    for (int i = 0; i < 4; i++) {
        unsigned int w = ue_words[lane * 4 + i];
        unsigned int lo = w & 0xFFFFu;
        unsigned int ex = (lo >> 7) & 0xFF;
        if (ex >= 100 && ex <= 132) cnt++;
    }
    for (int m = 1; m < 64; m <<= 1) cnt += __shfl_xor(cnt, m, 64);
    if (lane == 0) *flag = (cnt >= 128) ? 1 : 0;
}

// ---- init: E fp32 from inputs ----
__global__ __launch_bounds__(256) void k_init(const void* __restrict__ ue,
                                              const void* __restrict__ ie,
                                              const int* __restrict__ flag,
                                              float* __restrict__ E) {
    int idx = blockIdx.x * 256 + threadIdx.x;           // over NN*64
    if (idx >= NN * DD) return;
    int row = idx >> 6;
    bool isU = row < N_USERC;
    int si = isU ? idx : idx - N_USERC * DD;
    float v;
    if (*flag) {
        v = bf2f(isU ? ((const ushort_t*)ue)[si] : ((const ushort_t*)ie)[si]);
    } else {
        v = isU ? ((const float*)ue)[si] : ((const float*)ie)[si];
    }
    E[idx] = v;
}

// ---- E (fp32) -> Eb (bf16 gather copy); runs after phaseB (Eb aliases binned) ----
__global__ __launch_bounds__(256) void k_tobf(const float* __restrict__ E,
                                              ushort_t* __restrict__ Eb) {
    int idx = blockIdx.x * 256 + threadIdx.x;
    if (idx < NN * DD) Eb[idx] = f2bf(E[idx]);
}

// ---- zero the 147 bucket counters ----
__global__ __launch_bounds__(256) void k_zb(int* __restrict__ bucket_cnt) {
    if (threadIdx.x < NBKT) bucket_cnt[threadIdx.x] = 0;
}

// ---- bucket histogram: 147 buckets of 1024 rows ----
__global__ __launch_bounds__(256) void k_bhist(const int* __restrict__ rows,
                                               int* __restrict__ bucket_cnt) {
    __shared__ int h[NBKT];
    int t = threadIdx.x;
    if (t < NBKT) h[t] = 0;
    __syncthreads();
    int e0 = blockIdx.x * 4096;
#pragma unroll
    for (int i = 0; i < 16; i++) {
        int e = e0 + t + i * 256;
        if (e < NNZC) atomicAdd(&h[rows[e] >> 10], 1);
    }
    __syncthreads();
    if (t < NBKT && h[t]) atomicAdd(&bucket_cnt[t], h[t]);
}

// ---- exclusive scan of 147 bucket counts; seed bases/cursors ----
__global__ __launch_bounds__(256) void k_bscan(const int* __restrict__ bucket_cnt,
                                               int* __restrict__ gbase,
                                               int* __restrict__ gcursor,
                                               int* __restrict__ row_ptr) {
    __shared__ int s[256];
    int t = threadIdx.x;
    int v = (t < NBKT) ? bucket_cnt[t] : 0;
    s[t] = v; __syncthreads();
    for (int off = 1; off < 256; off <<= 1) {
        int x = (t >= off) ? s[t - off] : 0;
        __syncthreads();
        s[t] += x;
        __syncthreads();
    }
    if (t < NBKT) { int ex = s[t] - v; gbase[t] = ex; gcursor[t] = ex; }
    if (t == 0) { gbase[NBKT] = NNZC; row_ptr[NN] = NNZC; }
}

// ---- phase A: partition edges into 147 row-buckets ----
__global__ __launch_bounds__(256) void k_phaseA(const int* __restrict__ rows,
                                                const int* __restrict__ cols,
                                                const void* __restrict__ vals,
                                                const int* __restrict__ flag,
                                                int* __restrict__ gcursor,
                                                int2* __restrict__ binned) {
    __shared__ int hist[NBKT], base_[NBKT], lcur[NBKT];
    int t = threadIdx.x;
    int e0 = blockIdx.x * 4096;
    if (t < NBKT) { hist[t] = 0; lcur[t] = 0; }
    __syncthreads();
    int myrow[16];
#pragma unroll
    for (int i = 0; i < 16; i++) {
        int e = e0 + t + i * 256;
        int r = -1;
        if (e < NNZC) { r = rows[e]; atomicAdd(&hist[r >> 10], 1); }
        myrow[i] = r;
    }
    __syncthreads();
    if (t < NBKT && hist[t] > 0) base_[t] = atomicAdd(&gcursor[t], hist[t]);
    __syncthreads();
    int isbf = *flag;
#pragma unroll
    for (int i = 0; i < 16; i++) {
        int e = e0 + t + i * 256;
        if (e < NNZC) {
            int r = myrow[i];
            int bkt = r >> 10;
            int off = atomicAdd(&lcur[bkt], 1);
            int pos = base_[bkt] + off;
            int c = cols[e];
            float v = isbf ? bf2f(((const ushort_t*)vals)[e]) : ((const float*)vals)[e];
            // pack: row_local(10b) << 18 | col(18b); val bits separate
            binned[pos] = make_int2(((r & 1023) << 18) | c, __float_as_int(v));
        }
    }
}

// ---- phase B: one block per bucket; exact CSR slice via LDS hist+scan+cursor ----
__global__ __launch_bounds__(256) void k_phaseB(const int* __restrict__ gbase,
                                                const int2* __restrict__ binned,
                                                int2* __restrict__ ep,
                                                int* __restrict__ row_ptr) {
    __shared__ int rc[1024];    // counts -> inclusive scan
    __shared__ int rofs[1024];  // counts copy -> exclusive -> cursor
    int b = blockIdx.x, t = threadIdx.x;
    int s = gbase[b], e = gbase[b + 1];
    for (int i = t; i < 1024; i += 256) rc[i] = 0;
    __syncthreads();
    for (int i = s + t; i < e; i += 256)
        atomicAdd(&rc[binned[i].x >> 18], 1);
    __syncthreads();
    for (int i = t; i < 1024; i += 256) rofs[i] = rc[i];
    __syncthreads();
    for (int off = 1; off < 1024; off <<= 1) {
        int v[4];
#pragma unroll
        for (int j = 0; j < 4; j++) {
            int idx = t + j * 256;
            v[j] = (idx >= off) ? rc[idx - off] : 0;
        }
        __syncthreads();
#pragma unroll
        for (int j = 0; j < 4; j++) rc[t + j * 256] += v[j];
        __syncthreads();
    }
    for (int i = t; i < 1024; i += 256) {
        int ex = rc[i] - rofs[i];          // exclusive
        int gr = b * 1024 + i;
        if (gr < NN) row_ptr[gr] = s + ex;
        rofs[i] = ex;                      // becomes cursor
    }
    __syncthreads();
    for (int i = s + t; i < e; i += 256) {
        int2 en = binned[i];
        int rl = en.x >> 18;
        int c  = en.x & 0x3FFFF;
        int off = atomicAdd(&rofs[rl], 1);
        ep[s + off] = make_int2(c, en.y);
    }
}

// ---- SpMM v3 (control, unchanged): oct-gather, 16 edges in flight ----
__global__ __launch_bounds__(256) void k_spmm(const int* __restrict__ row_ptr,
                                              const int2* __restrict__ ep,
                                              const ushort_t* __restrict__ Eb,
                                              float* __restrict__ LE) {
    int wv = threadIdx.x >> 6;
    int r = blockIdx.x * 4 + wv;               // 37500*4 = 150000 exact
    int lane = threadIdx.x & 63;
    int oct = lane >> 3;                       // edge slot 0..7
    int d8  = (lane & 7) * 8;                  // dims d8..d8+7
    int s = __builtin_amdgcn_readfirstlane(row_ptr[r]);
    int e = __builtin_amdgcn_readfirstlane(row_ptr[r + 1]);
    float acc[8];
#pragma unroll
    for (int k = 0; k < 8; k++) acc[k] = 0.f;
    for (int i = s; i < e; i += 16) {
#pragma unroll
        for (int v = 0; v < 2; v++) {
            int idx = i + v * 8 + oct;
            bool valid = idx < e;
            int j = valid ? idx : s;
            int2 pv = ep[j];
            float w = valid ? __int_as_float(pv.y) : 0.f;
            uint4 q = *(const uint4*)(Eb + (size_t)pv.x * DD + d8);
            acc[0] = fmaf(w, __uint_as_float(q.x << 16),          acc[0]);
            acc[1] = fmaf(w, __uint_as_float(q.x & 0xffff0000u),  acc[1]);
            acc[2] = fmaf(w, __uint_as_float(q.y << 16),          acc[2]);
            acc[3] = fmaf(w, __uint_as_float(q.y & 0xffff0000u),  acc[3]);
            acc[4] = fmaf(w, __uint_as_float(q.z << 16),          acc[4]);
            acc[5] = fmaf(w, __uint_as_float(q.z & 0xffff0000u),  acc[5]);
            acc[6] = fmaf(w, __uint_as_float(q.w << 16),          acc[6]);
            acc[7] = fmaf(w, __uint_as_float(q.w & 0xffff0000u),  acc[7]);
        }
    }
#pragma unroll
    for (int m = 8; m < 64; m <<= 1)
#pragma unroll
        for (int k = 0; k < 8; k++) acc[k] += __shfl_xor(acc[k], m, 64);
    if (oct == 0) {
        float* dst = LE + (size_t)r * DD + d8;
        *(float4*)dst       = make_float4(acc[0], acc[1], acc[2], acc[3]);
        *(float4*)(dst + 4) = make_float4(acc[4], acc[5], acc[6], acc[7]);
    }
}

// ---- dense v3: lane = col; W1/W2 columns in 128 VGPRs; x1/x2 staged in LDS
// and broadcast via wave-uniform ds_read_b128 into uniform VGPRs feeding FMA
// directly (zero readlane). 4-row accumulator rotation kills dep stalls.
// Block = 64-row tile; each wave does 16 rows (4 groups of 4). ----
__global__ __launch_bounds__(256, 2) void k_dense3(const float* __restrict__ LE,
                                                   float* __restrict__ E,
                                                   ushort_t* __restrict__ Eb,
                                                   const void* __restrict__ W1b,
                                                   const void* __restrict__ W2b,
                                                   const void* __restrict__ b1b,
                                                   const void* __restrict__ b2b,
                                                   const int* __restrict__ flag,
                                                   int layer) {
    __shared__ __align__(16) float xs1[64][64];
    __shared__ __align__(16) float xs2[64][64];

    int tid = threadIdx.x;
    int lane = tid & 63, wv = tid >> 6;
    int isbf = *flag;

    // W columns into registers (lane = col), k compile-time
    float w1r[64], w2r[64];
    size_t Wo = (size_t)layer * 4096 + lane;
#pragma unroll
    for (int k = 0; k < 64; k++) {
        w1r[k] = isbf ? bf2f(((const ushort_t*)W1b)[Wo + (size_t)k * 64])
                      : ((const float*)W1b)[Wo + (size_t)k * 64];
        w2r[k] = isbf ? bf2f(((const ushort_t*)W2b)[Wo + (size_t)k * 64])
                      : ((const float*)W2b)[Wo + (size_t)k * 64];
    }
    size_t bo = (size_t)layer * 64 + lane;
    float bias = (isbf ? bf2f(((const ushort_t*)b1b)[bo]) : ((const float*)b1b)[bo])
               + (isbf ? bf2f(((const ushort_t*)b2b)[bo]) : ((const float*)b2b)[bo]);

    int r0 = blockIdx.x * 64;

    // stage x1/x2 for 64 rows: 1024 float4 granules over 256 threads
#pragma unroll
    for (int j = 0; j < 4; j++) {
        int i = tid + j * 256;            // granule id 0..1023
        int row = i >> 4;
        int k4  = (i & 15) * 4;
        int gr = r0 + row;
        if (gr < NN) {
            float4v l4 = *(const float4v*)(LE + (size_t)gr * DD + k4);
            float4v e4 = *(const float4v*)(E  + (size_t)gr * DD + k4);
            float4v x1, x2;
#pragma unroll
            for (int u = 0; u < 4; u++) { x1[u] = l4[u] + e4[u]; x2[u] = l4[u] * e4[u]; }
            *(float4v*)&xs1[row][k4] = x1;
            *(float4v*)&xs2[row][k4] = x2;
        }
    }
    __syncthreads();

#pragma unroll
    for (int g = 0; g < 4; g++) {
        int rowb = wv * 16 + g * 4;       // local row base (4 rows)
        float a0 = 0.f, a1 = 0.f, a2 = 0.f, a3 = 0.f;
#pragma unroll
        for (int k4 = 0; k4 < 64; k4 += 4) {
            float4v p10 = *(const float4v*)&xs1[rowb + 0][k4];
            float4v p11 = *(const float4v*)&xs1[rowb + 1][k4];
            float4v p12 = *(const float4v*)&xs1[rowb + 2][k4];
            float4v p13 = *(const float4v*)&xs1[rowb + 3][k4];
            float4v p20 = *(const float4v*)&xs2[rowb + 0][k4];
            float4v p21 = *(const float4v*)&xs2[rowb + 1][k4];
            float4v p22 = *(const float4v*)&xs2[rowb + 2][k4];
            float4v p23 = *(const float4v*)&xs2[rowb + 3][k4];
#pragma unroll
            for (int u = 0; u < 4; u++) {
                float w1 = w1r[k4 + u], w2 = w2r[k4 + u];
                a0 = fmaf(p10[u], w1, a0);
                a1 = fmaf(p11[u], w1, a1);
                a2 = fmaf(p12[u], w1, a2);
                a3 = fmaf(p13[u], w1, a3);
                a0 = fmaf(p20[u], w2, a0);
                a1 = fmaf(p21[u], w2, a1);
                a2 = fmaf(p22[u], w2, a2);
                a3 = fmaf(p23[u], w2, a3);
            }
        }
        // epilogue: bias + leaky, store E (fp32) and Eb (bf16)
        float h[4] = {a0, a1, a2, a3};
#pragma unroll
        for (int j = 0; j < 4; j++) {
            int gr = r0 + rowb + j;
            if (gr < NN) {
                float v = h[j] + bias;
                v = (v >= 0.f) ? v : 0.2f * v;
                E[(size_t)gr * DD + lane] = v;
                Eb[(size_t)gr * DD + lane] = f2bf(v);
            }
        }
    }
}

static __device__ __forceinline__ int rid_to_node(int rid,
                                                  const int* users, const int* pos, const int* neg) {
    if (rid < BB)      return users[rid] - 1;
    if (rid < 2 * BB)  return N_USERC + pos[rid - BB] - 1;
    return N_USERC + neg[rid - 2 * BB] - 1;
}

// ---- slice 0 of output: raw initial embedding (fp32) of gathered rows ----
__global__ __launch_bounds__(256) void k_outslice0(const float* __restrict__ E,
                                                   const int* __restrict__ users,
                                                   const int* __restrict__ pos,
                                                   const int* __restrict__ neg,
                                                   float* __restrict__ out) {
    int rid  = blockIdx.x * 4 + (threadIdx.x >> 6);
    int lane = threadIdx.x & 63;
    if (rid >= NRID) return;
    int node = rid_to_node(rid, users, pos, neg);
    out[(size_t)rid * 256 + lane] = E[(size_t)node * DD + lane];
}

// ---- slice l+1: normalized current E of gathered rows (fp32) ----
__global__ __launch_bounds__(256) void k_outnorm(const float* __restrict__ E,
                                                 const int* __restrict__ users,
                                                 const int* __restrict__ pos,
                                                 const int* __restrict__ neg,
                                                 float* __restrict__ out,
                                                 int cbase) {
    int rid  = blockIdx.x * 4 + (threadIdx.x >> 6);
    int lane = threadIdx.x & 63;
    if (rid >= NRID) return;
    int node = rid_to_node(rid, users, pos, neg);
    float v = E[(size_t)node * DD + lane];
    float p2 = v * v;
    for (int m = 1; m < 64; m <<= 1) p2 += __shfl_xor(p2, m, 64);
    float nr = fmaxf(sqrtf(p2), 1e-12f);
    out[(size_t)rid * 256 + cbase + lane] = v / nr;
}

extern "C" void kernel_launch(void* const* d_in, const int* in_sizes, int n_in,
                              void* d_out, int out_size, void* d_ws, size_t ws_size,
                              hipStream_t stream) {
    const void* ue   = d_in[0];
    const void* ie   = d_in[1];
    const void* ev   = d_in[2];
    const void* W1   = d_in[3];
    const void* b1   = d_in[4];
    const void* W2   = d_in[5];
    const void* b2   = d_in[6];
    const int*  ei   = (const int*)d_in[7];
    const int*  usr  = (const int*)d_in[8];
    const int*  posi = (const int*)d_in[9];
    const int*  negi = (const int*)d_in[10];
    float*      out  = (float*)d_out;          // reference output dtype = fp32

    const int* rows = ei;
    const int* cols = ei + NNZC;

    // workspace carve — total ~116 MB (Eb aliases binned: binned is dead after phaseB)
    char* w = (char*)d_ws;
    float*  E         = (float*)w;  w += (size_t)NN * DD * 4;    // 38.4 MB
    float*  LE        = (float*)w;  w += (size_t)NN * DD * 4;    // 38.4 MB
    int2*   binned    = (int2*)w;   w += (size_t)NNZC * 8;       // 19.2 MB
    ushort_t* Eb      = (ushort_t*)binned;                       // alias (19.2 MB need)
    int2*   ep        = (int2*)w;   w += (size_t)NNZC * 8;       // 19.2 MB
    int*    row_ptr   = (int*)w;    w += 600320;                 // NN+1 ints padded
    int*    gbase     = (int*)w;    w += 1024;                   // NBKT+1
    int*    gcursor   = (int*)w;    w += 1024;
    int*    bucket_cnt= (int*)w;    w += 1024;
    int*    flag      = (int*)w;    w += 256;

    k_sniff<<<1, 64, 0, stream>>>((const unsigned int*)ue, flag);
    k_init<<<37500, 256, 0, stream>>>(ue, ie, flag, E);
    k_zb<<<1, 256, 0, stream>>>(bucket_cnt);
    k_bhist<<<NABLK, 256, 0, stream>>>(rows, bucket_cnt);
    k_bscan<<<1, 256, 0, stream>>>(bucket_cnt, gbase, gcursor, row_ptr);
    k_phaseA<<<NABLK, 256, 0, stream>>>(rows, cols, ev, flag, gcursor, binned);
    k_phaseB<<<NBKT, 256, 0, stream>>>(gbase, binned, ep, row_ptr);
    k_tobf<<<37500, 256, 0, stream>>>(E, Eb);      // after phaseB: binned is dead

    k_outslice0<<<3072, 256, 0, stream>>>(E, usr, posi, negi, out);

    for (int l = 0; l < NLAYER; l++) {
        k_spmm<<<37500, 256, 0, stream>>>(row_ptr, ep, Eb, LE);
        k_dense3<<<NDTILE, 256, 0, stream>>>(LE, E, Eb, W1, W2, b1, b2, flag, l);
        k_outnorm<<<3072, 256, 0, stream>>>(E, usr, posi, negi, out, 64 * (l + 1));
    }
}